// Round 10
// baseline (140.640 us; speedup 1.0000x reference)
//
#include <hip/hip_runtime.h>
#include <stdint.h>

// Problem constants
#define BB 16
#define TT 4096
#define HH 64
#define MM 640    // HH*DD

// ---------------------------------------------------------------------------
// Kernel 1: ksum[b][m] = sum_t key[b][t][m]  (~26-27 us, near read roofline)
// ---------------------------------------------------------------------------
__global__ void __launch_bounds__(256)
ksum_kernel(const float* __restrict__ key, float* __restrict__ ksum) {
    int g = blockIdx.x * blockDim.x + threadIdx.x;   // b*160 + c
    int b = g / 160;
    int c = g % 160;
    int t0 = blockIdx.y * 32;

    const float4* p = reinterpret_cast<const float4*>(key)
                    + (size_t)b * TT * 160 + (size_t)t0 * 160 + c;

    float4 a0 = make_float4(0.f,0.f,0.f,0.f);
    float4 a1 = make_float4(0.f,0.f,0.f,0.f);
    float4 a2 = make_float4(0.f,0.f,0.f,0.f);
    float4 a3 = make_float4(0.f,0.f,0.f,0.f);
    #pragma unroll
    for (int i = 0; i < 32; i += 4) {
        float4 x0 = p[(size_t)(i + 0) * 160];
        float4 x1 = p[(size_t)(i + 1) * 160];
        float4 x2 = p[(size_t)(i + 2) * 160];
        float4 x3 = p[(size_t)(i + 3) * 160];
        a0.x += x0.x; a0.y += x0.y; a0.z += x0.z; a0.w += x0.w;
        a1.x += x1.x; a1.y += x1.y; a1.z += x1.z; a1.w += x1.w;
        a2.x += x2.x; a2.y += x2.y; a2.z += x2.z; a2.w += x2.w;
        a3.x += x3.x; a3.y += x3.y; a3.z += x3.z; a3.w += x3.w;
    }
    float sx = (a0.x + a1.x) + (a2.x + a3.x);
    float sy = (a0.y + a1.y) + (a2.y + a3.y);
    float sz = (a0.z + a1.z) + (a2.z + a3.z);
    float sw = (a0.w + a1.w) + (a2.w + a3.w);

    float* dst = ksum + b * MM + c * 4;
    atomicAdd(dst + 0, sx);
    atomicAdd(dst + 1, sy);
    atomicAdd(dst + 2, sz);
    atomicAdd(dst + 3, sw);
}

// ---------------------------------------------------------------------------
// Robust tanh via rcp (exp of negative arg only -> never overflows)
// ---------------------------------------------------------------------------
__device__ __forceinline__ float tanh_rcp(float x) {
    float ax = fabsf(x);
    float e2 = __expf(-2.0f * ax);
    float th = (1.0f - e2) * __builtin_amdgcn_rcpf(1.0f + e2);
    return copysignf(th, x);
}

// ---------------------------------------------------------------------------
// Kernel 2: pure streaming, NO LDS, NO barriers, NO vmcnt(0) drains.
// Thread = (b, t, head-pair): a head-pair is 20 floats = 5 aligned float4.
//   loads : 5 q-float4 + 5 v-float4 straight to registers; waves consume
//           them via compiler-counted vmcnt -> continuous issue, never a
//           full drain, waves desynchronize -> memory always busy.
//   lanes : hp fastest (32 hp = full 2560B row; 2 rows per wave) -> every
//           64B line fully consumed by the wave within 5 instr slots.
//   stores: 2 scalar floats, 16KB apart; L2 write-back merges siblings
//           (measured 2x amp in R8 = +16MB, ~+3us -- acceptable).
// ---------------------------------------------------------------------------
__global__ void __launch_bounds__(256)
attn_kernel(const float* __restrict__ q,
            const float* __restrict__ v,
            const float* __restrict__ ksum,
            float* __restrict__ out) {
    const int u  = blockIdx.x * 256 + threadIdx.x;   // unit index
    const int hp = u & 31;                           // head pair 0..31
    const int t  = (u >> 5) & (TT - 1);
    const int b  = u >> 17;

    const float4* qp = reinterpret_cast<const float4*>(
        q + ((size_t)b * TT + t) * MM + hp * 20);
    const float4* vp = reinterpret_cast<const float4*>(
        v + ((size_t)b * TT + t) * MM + hp * 20);
    const float4* kp = reinterpret_cast<const float4*>(
        ksum + (size_t)b * MM + hp * 20);

    // issue all 10 streaming loads back-to-back (independent dests)
    float4 rq[5], rv[5], rk[5];
    #pragma unroll
    for (int j = 0; j < 5; ++j) rq[j] = qp[j];
    #pragma unroll
    for (int j = 0; j < 5; ++j) rv[j] = vp[j];
    #pragma unroll
    for (int j = 0; j < 5; ++j) rk[j] = kp[j];      // L1/L2-hot 40KB table

    const float* qf = reinterpret_cast<const float*>(rq);
    const float* vf = reinterpret_cast<const float*>(rv);
    const float* kf = reinterpret_cast<const float*>(rk);
    const float R = 0.316227766016838f;              // 1/sqrt(10)

    float res[2];
    #pragma unroll
    for (int h = 0; h < 2; ++h) {
        float sum = 0.f, dot = 0.f;
        #pragma unroll
        for (int d = 0; d < 10; ++d) {
            int j = h * 10 + d;                      // compile-time constant
            float e = __expf(tanh_rcp(qf[j] * kf[j] * R));
            sum += e;
            dot += e * vf[j];
        }
        res[h] = dot * __builtin_amdgcn_rcpf(sum);
    }

    float* ob = out + ((size_t)(b * HH + hp * 2)) * TT + t;
    ob[0]  = res[0];
    ob[TT] = res[1];
}

// ---------------------------------------------------------------------------
extern "C" void kernel_launch(void* const* d_in, const int* in_sizes, int n_in,
                              void* d_out, int out_size, void* d_ws, size_t ws_size,
                              hipStream_t stream) {
    const float* q = (const float*)d_in[0];
    const float* k = (const float*)d_in[1];
    const float* v = (const float*)d_in[2];
    // d_in[3] = W, d_in[4] = b : dead code (softmax over size-1 axis == 1)
    float* out  = (float*)d_out;
    float* ksum = (float*)d_ws;    // B*M floats = 40 KB

    hipMemsetAsync(d_ws, 0, (size_t)BB * MM * sizeof(float), stream);
    ksum_kernel<<<dim3(10, 128), dim3(256), 0, stream>>>(k, ksum);
    // 16*4096*32 units / 256 = 8192 blocks
    attn_kernel<<<dim3(8192), dim3(256), 0, stream>>>(q, v, ksum, out);
}

// Round 11
// 112.882 us; speedup vs baseline: 1.2459x; 1.2459x over previous
//
#include <hip/hip_runtime.h>
#include <stdint.h>

// Problem constants
#define BB 16
#define TT 4096
#define HH 64
#define MM 640    // HH*DD

#define TROWS 16          // t-rows per attn tile
#define PADF4 41          // LDS row stride in float4 (656 B)

// ---------------------------------------------------------------------------
// Kernel 1: ksum[b][m] = sum_t key[b][t][m]  (~30 us, near its roofline)
// ---------------------------------------------------------------------------
__global__ void __launch_bounds__(256)
ksum_kernel(const float* __restrict__ key, float* __restrict__ ksum) {
    int g = blockIdx.x * blockDim.x + threadIdx.x;   // b*160 + c
    int b = g / 160;
    int c = g % 160;
    int t0 = blockIdx.y * 32;

    const float4* p = reinterpret_cast<const float4*>(key)
                    + (size_t)b * TT * 160 + (size_t)t0 * 160 + c;

    float4 a0 = make_float4(0.f,0.f,0.f,0.f);
    float4 a1 = make_float4(0.f,0.f,0.f,0.f);
    float4 a2 = make_float4(0.f,0.f,0.f,0.f);
    float4 a3 = make_float4(0.f,0.f,0.f,0.f);
    #pragma unroll
    for (int i = 0; i < 32; i += 4) {
        float4 x0 = p[(size_t)(i + 0) * 160];
        float4 x1 = p[(size_t)(i + 1) * 160];
        float4 x2 = p[(size_t)(i + 2) * 160];
        float4 x3 = p[(size_t)(i + 3) * 160];
        a0.x += x0.x; a0.y += x0.y; a0.z += x0.z; a0.w += x0.w;
        a1.x += x1.x; a1.y += x1.y; a1.z += x1.z; a1.w += x1.w;
        a2.x += x2.x; a2.y += x2.y; a2.z += x2.z; a2.w += x2.w;
        a3.x += x3.x; a3.y += x3.y; a3.z += x3.z; a3.w += x3.w;
    }
    float sx = (a0.x + a1.x) + (a2.x + a3.x);
    float sy = (a0.y + a1.y) + (a2.y + a3.y);
    float sz = (a0.z + a1.z) + (a2.z + a3.z);
    float sw = (a0.w + a1.w) + (a2.w + a3.w);

    float* dst = ksum + b * MM + c * 4;
    atomicAdd(dst + 0, sx);
    atomicAdd(dst + 1, sy);
    atomicAdd(dst + 2, sz);
    atomicAdd(dst + 3, sw);
}

// ---------------------------------------------------------------------------
// Robust tanh via rcp (exp of negative arg only -> never overflows)
// ---------------------------------------------------------------------------
__device__ __forceinline__ float tanh_rcp(float x) {
    float ax = fabsf(x);
    float e2 = __expf(-2.0f * ax);
    float th = (1.0f - e2) * __builtin_amdgcn_rcpf(1.0f + e2);
    return copysignf(th, x);
}

// ---------------------------------------------------------------------------
// Kernel 2: R8 structure, request-minimized.
//   - q/v: 10 coalesced float4/thread (compulsory 160 B) -> regs -> LDS
//   - ksum: ONE float4 instruction per block stages the 640B slice to LDS
//           (replaces 80 B + ~40 scattered transactions PER THREAD in R8);
//           threads read their head row from LDS (broadcast within group)
//   - stores: 64B segments (unchanged)
// Total vmem: 168 B/thread vs 248; ~195 transactions/wave vs ~590.
// ---------------------------------------------------------------------------
__global__ void __launch_bounds__(128)
attn_kernel(const float* __restrict__ q,
            const float* __restrict__ v,
            const float* __restrict__ ksum,
            float* __restrict__ out) {
    __shared__ float qs[TROWS * PADF4 * 4];
    __shared__ float vs[TROWS * PADF4 * 4];
    __shared__ float ks_lds[160];

    const int tid = threadIdx.x;          // 0..127
    const int t0  = blockIdx.x * TROWS;
    const int hg  = blockIdx.y;
    const int b   = blockIdx.z;

    const float4* qg = reinterpret_cast<const float4*>(q)
                     + ((size_t)(b * TT + t0)) * 160 + hg * 40;
    const float4* vg = reinterpret_cast<const float4*>(v)
                     + ((size_t)(b * TT + t0)) * 160 + hg * 40;

    // ---- stage: 5+5 float4 into regs (back-to-back), plus ksum slice ----
    float4 rq[5], rv[5];
    #pragma unroll
    for (int j = 0; j < 5; ++j) {
        int idx = tid + 128 * j;          // 0..639
        int row = idx / 40;
        int c   = idx % 40;
        rq[j] = qg[(size_t)row * 160 + c];
        rv[j] = vg[(size_t)row * 160 + c];
    }
    if (tid < 40) {
        reinterpret_cast<float4*>(ks_lds)[tid] =
            reinterpret_cast<const float4*>(ksum + b * MM + hg * 160)[tid];
    }

    float4* qs4 = reinterpret_cast<float4*>(qs);
    float4* vs4 = reinterpret_cast<float4*>(vs);
    #pragma unroll
    for (int j = 0; j < 5; ++j) {
        int idx = tid + 128 * j;
        int row = idx / 40;
        int c   = idx % 40;
        qs4[row * PADF4 + c] = rq[j];
        vs4[row * PADF4 + c] = rv[j];
    }
    __syncthreads();

    // ---- per-thread ksum rows from LDS (broadcast within 16-lane groups) ----
    const float R = 0.316227766016838f;   // 1/sqrt(10)
    const int head0 = tid >> 4;           // 0..7 (second head = +8)
    const int row   = tid & 15;

    float ksr0[10], ksr1[10];
    #pragma unroll
    for (int d = 0; d < 10; ++d) {
        ksr0[d] = ks_lds[head0 * 10 + d] * R;
        ksr1[d] = ks_lds[(head0 + 8) * 10 + d] * R;
    }

    // ---- compute: 2 (row, head) outputs per thread ----
    #pragma unroll
    for (int o = 0; o < 2; ++o) {
        const int head  = head0 + o * 8;
        const int lbase = row * (PADF4 * 4) + head * 10;
        const float* kk = o ? ksr1 : ksr0;
        float sum = 0.f, dot = 0.f;
        #pragma unroll
        for (int d = 0; d < 10; ++d) {
            float e = __expf(tanh_rcp(qs[lbase + d] * kk[d]));
            sum += e;
            dot += e * vs[lbase + d];
        }
        out[((size_t)(b * HH + hg * 16 + head)) * TT + t0 + row]
            = dot * __builtin_amdgcn_rcpf(sum);
    }
}

// ---------------------------------------------------------------------------
extern "C" void kernel_launch(void* const* d_in, const int* in_sizes, int n_in,
                              void* d_out, int out_size, void* d_ws, size_t ws_size,
                              hipStream_t stream) {
    const float* q = (const float*)d_in[0];
    const float* k = (const float*)d_in[1];
    const float* v = (const float*)d_in[2];
    // d_in[3] = W, d_in[4] = b : dead code (softmax over size-1 axis == 1)
    float* out  = (float*)d_out;
    float* ksum = (float*)d_ws;    // B*M floats = 40 KB

    hipMemsetAsync(d_ws, 0, (size_t)BB * MM * sizeof(float), stream);
    ksum_kernel<<<dim3(10, 128), dim3(256), 0, stream>>>(k, ksum);
    attn_kernel<<<dim3(TT / TROWS, 4, BB), dim3(128), 0, stream>>>(q, v, ksum, out);
}